// Round 1
// baseline (42.480 us; speedup 1.0000x reference)
//
#include <hip/hip_runtime.h>
#include <math.h>

#define EPSF 1e-6f

// Problem constants (fixed by setup_inputs): B=2, K=3, D=H=W=96.
constexpr int kB  = 2;
constexpr int kS  = 96 * 96 * 96;   // spatial voxels per batch = 884736
constexpr int kS4 = kS / 4;         // float4 units per channel plane

// Per-voxel math, exact port of the JAX reference (f32).
__device__ __forceinline__ void voxel_math(
    float qw, float qx, float qy, float qz,        // q channels
    float pw, float px, float py, float pz,        // q_ref channels
    float r0, float r1, float r2,                  // r channels (K=3)
    float rr0, float rr1, float rr2,               // r_ref channels
    float gw0, float gw1, float gw2, float gw3, float gb,
    float* U9, float* R3, float* Q4)
{
    // qv = q / (||q|| + EPS)
    float n   = sqrtf(qw*qw + qx*qx + qy*qy + qz*qz) + EPSF;
    float inv = 1.0f / n;
    float aw = qw*inv, ax = qx*inv, ay = qy*inv, az = qz*inv;
    n   = sqrtf(pw*pw + px*px + py*py + pz*pz) + EPSF;
    inv = 1.0f / n;
    float bw = pw*inv, bx = px*inv, by = py*inv, bz = pz*inv;

    // c = clip(|<qv,qv_ref>|, 0, 1)
    float d0 = aw*bw + ax*bx + ay*by + az*bz;
    float c  = fminf(fabsf(d0), 1.0f);

    // gate: omega = sigmoid(gw0*r_mean + gw1*r_mean_ref + gw2*c + gw3 + gb)
    float rm   = (r0 + r1 + r2)   * (1.0f / 3.0f);
    float rmr  = (rr0 + rr1 + rr2) * (1.0f / 3.0f);
    float zlin = gw0*rm + gw1*rmr + gw2*c + gw3 + gb;
    float omega = 1.0f / (1.0f + expf(-zlin));

    // slerp(qv, qv_ref, t=omega)
    float sgn = (d0 < 0.0f) ? -1.0f : 1.0f;
    float q1w = sgn*bw, q1x = sgn*bx, q1y = sgn*by, q1z = sgn*bz;
    float dd    = fminf(fabsf(d0), 1.0f - 1e-7f);
    float theta = acosf(dd);
    float st    = sinf(theta);
    bool  small = st < 1e-4f;
    float invsafe = small ? 1.0f : (1.0f / st);
    float t  = omega;
    float s0 = sinf(t * theta);
    float s1 = sinf((1.0f - t) * theta);

    float sw = (s0*aw + s1*q1w) * invsafe;
    float sx = (s0*ax + s1*q1x) * invsafe;
    float sy = (s0*ay + s1*q1y) * invsafe;
    float sz = (s0*az + s1*q1z) * invsafe;
    float lw = t*aw + (1.0f - t)*q1w;
    float lx = t*ax + (1.0f - t)*q1x;
    float ly = t*ay + (1.0f - t)*q1y;
    float lz = t*az + (1.0f - t)*q1z;
    float ow = small ? lw : sw;
    float ox = small ? lx : sx;
    float oy = small ? ly : sy;
    float oz = small ? lz : sz;

    // q_bar = out / (||out|| + EPS)
    n   = sqrtf(ow*ow + ox*ox + oy*oy + oz*oz) + EPSF;
    inv = 1.0f / n;
    float w = ow*inv, x = ox*inv, y = oy*inv, z = oz*inv;

    Q4[0] = w; Q4[1] = x; Q4[2] = y; Q4[3] = z;

    // R_bar from quaternion
    float xx = x*x, yy = y*y, zz = z*z;
    float xy = x*y, xz = x*z, yz = y*z;
    float wx = w*x, wy = w*y, wz = w*z;
    float m00 = 1.0f - 2.0f*(yy + zz), m01 = 2.0f*(xy - wz), m02 = 2.0f*(xz + wy);
    float m10 = 2.0f*(xy + wz), m11 = 1.0f - 2.0f*(xx + zz), m12 = 2.0f*(yz - wx);
    float m20 = 2.0f*(xz - wy), m21 = 2.0f*(yz + wx), m22 = 1.0f - 2.0f*(xx + yy);

    // Rn: normalize each COLUMN j (norm over row axis), +EPS
    float c0 = 1.0f / (sqrtf(m00*m00 + m10*m10 + m20*m20) + EPSF);
    float c1 = 1.0f / (sqrtf(m01*m01 + m11*m11 + m21*m21) + EPSF);
    float c2 = 1.0f / (sqrtf(m02*m02 + m12*m12 + m22*m22) + EPSF);

    // U_bar[b, j, i, ...] = Rn[i][j]  (channel index = j*3 + i)
    U9[0] = m00*c0; U9[1] = m10*c0; U9[2] = m20*c0;   // j=0
    U9[3] = m01*c1; U9[4] = m11*c1; U9[5] = m21*c1;   // j=1
    U9[6] = m02*c2; U9[7] = m12*c2; U9[8] = m22*c2;   // j=2

    // r_bar = omega*r + (1-omega)*r_ref
    float om1 = 1.0f - omega;
    R3[0] = omega*r0 + om1*rr0;
    R3[1] = omega*r1 + om1*rr1;
    R3[2] = omega*r2 + om1*rr2;
}

__global__ __launch_bounds__(256) void ConsensusField3D_78013785964619_kernel(
    const float* __restrict__ r,
    const float* __restrict__ q,
    const float* __restrict__ r_ref,
    const float* __restrict__ q_ref,
    const float* __restrict__ gate_w,
    const float* __restrict__ gate_b,
    float* __restrict__ out)
{
    int idx = blockIdx.x * blockDim.x + threadIdx.x;
    if (idx >= kB * kS4) return;
    int b  = idx / kS4;
    int s4 = idx - b * kS4;

    const float4* q4  = (const float4*)q;
    const float4* p4  = (const float4*)q_ref;
    const float4* ra4 = (const float4*)r;
    const float4* rb4 = (const float4*)r_ref;

    // Coalesced float4 loads: 4 consecutive voxels per thread, per channel.
    float4 vqw = q4[(b*4 + 0)*kS4 + s4];
    float4 vqx = q4[(b*4 + 1)*kS4 + s4];
    float4 vqy = q4[(b*4 + 2)*kS4 + s4];
    float4 vqz = q4[(b*4 + 3)*kS4 + s4];
    float4 vpw = p4[(b*4 + 0)*kS4 + s4];
    float4 vpx = p4[(b*4 + 1)*kS4 + s4];
    float4 vpy = p4[(b*4 + 2)*kS4 + s4];
    float4 vpz = p4[(b*4 + 3)*kS4 + s4];
    float4 vr0 = ra4[(b*3 + 0)*kS4 + s4];
    float4 vr1 = ra4[(b*3 + 1)*kS4 + s4];
    float4 vr2 = ra4[(b*3 + 2)*kS4 + s4];
    float4 vs0 = rb4[(b*3 + 0)*kS4 + s4];
    float4 vs1 = rb4[(b*3 + 1)*kS4 + s4];
    float4 vs2 = rb4[(b*3 + 2)*kS4 + s4];

    float gw0 = gate_w[0], gw1 = gate_w[1], gw2 = gate_w[2], gw3 = gate_w[3];
    float gb  = gate_b[0];

    float qwA[4] = {vqw.x, vqw.y, vqw.z, vqw.w};
    float qxA[4] = {vqx.x, vqx.y, vqx.z, vqx.w};
    float qyA[4] = {vqy.x, vqy.y, vqy.z, vqy.w};
    float qzA[4] = {vqz.x, vqz.y, vqz.z, vqz.w};
    float pwA[4] = {vpw.x, vpw.y, vpw.z, vpw.w};
    float pxA[4] = {vpx.x, vpx.y, vpx.z, vpx.w};
    float pyA[4] = {vpy.x, vpy.y, vpy.z, vpy.w};
    float pzA[4] = {vpz.x, vpz.y, vpz.z, vpz.w};
    float r0A[4] = {vr0.x, vr0.y, vr0.z, vr0.w};
    float r1A[4] = {vr1.x, vr1.y, vr1.z, vr1.w};
    float r2A[4] = {vr2.x, vr2.y, vr2.z, vr2.w};
    float s0A[4] = {vs0.x, vs0.y, vs0.z, vs0.w};
    float s1A[4] = {vs1.x, vs1.y, vs1.z, vs1.w};
    float s2A[4] = {vs2.x, vs2.y, vs2.z, vs2.w};

    float U9[9][4], R3[3][4], Q4[4][4];

    #pragma unroll
    for (int j = 0; j < 4; ++j) {
        float u[9], rb_[3], qb_[4];
        voxel_math(qwA[j], qxA[j], qyA[j], qzA[j],
                   pwA[j], pxA[j], pyA[j], pzA[j],
                   r0A[j], r1A[j], r2A[j],
                   s0A[j], s1A[j], s2A[j],
                   gw0, gw1, gw2, gw3, gb,
                   u, rb_, qb_);
        #pragma unroll
        for (int k = 0; k < 9; ++k) U9[k][j] = u[k];
        #pragma unroll
        for (int k = 0; k < 3; ++k) R3[k][j] = rb_[k];
        #pragma unroll
        for (int k = 0; k < 4; ++k) Q4[k][j] = qb_[k];
    }

    float4* o4 = (float4*)out;
    const int RB = kB * 9 * kS4;        // start of r_bar, in float4 units
    const int QB = RB + kB * 3 * kS4;   // start of q_out

    #pragma unroll
    for (int ch = 0; ch < 9; ++ch)
        o4[(b*9 + ch)*kS4 + s4] = make_float4(U9[ch][0], U9[ch][1], U9[ch][2], U9[ch][3]);
    #pragma unroll
    for (int ch = 0; ch < 3; ++ch)
        o4[RB + (b*3 + ch)*kS4 + s4] = make_float4(R3[ch][0], R3[ch][1], R3[ch][2], R3[ch][3]);
    #pragma unroll
    for (int ch = 0; ch < 4; ++ch)
        o4[QB + (b*4 + ch)*kS4 + s4] = make_float4(Q4[ch][0], Q4[ch][1], Q4[ch][2], Q4[ch][3]);
}

extern "C" void kernel_launch(void* const* d_in, const int* in_sizes, int n_in,
                              void* d_out, int out_size, void* d_ws, size_t ws_size,
                              hipStream_t stream) {
    // Input order per setup_inputs: U(0), r(1), q(2), U_ref(3), r_ref(4), q_ref(5),
    // gate_w(6), gate_b(7). U and U_ref are DEAD (never used by the reference).
    const float* r      = (const float*)d_in[1];
    const float* q      = (const float*)d_in[2];
    const float* r_ref  = (const float*)d_in[4];
    const float* q_ref  = (const float*)d_in[5];
    const float* gate_w = (const float*)d_in[6];
    const float* gate_b = (const float*)d_in[7];
    float* out = (float*)d_out;

    const int total  = kB * kS4;              // 442368 threads
    const int block  = 256;
    const int grid   = (total + block - 1) / block;
    ConsensusField3D_78013785964619_kernel<<<grid, block, 0, stream>>>(
        r, q, r_ref, q_ref, gate_w, gate_b, out);
}

// Round 3
// 36.809 us; speedup vs baseline: 1.1541x; 1.1541x over previous
//
#include <hip/hip_runtime.h>
#include <math.h>

#define EPSF 1e-6f

// Problem constants (fixed by setup_inputs): B=2, K=3, D=H=W=96.
constexpr int kB  = 2;
constexpr int kS  = 96 * 96 * 96;   // spatial voxels per batch = 884736
constexpr int kS4 = kS / 4;         // float4 units per channel plane

// Native vector type for nontemporal stores (__builtin_nontemporal_store
// rejects HIP's class-type float4).
typedef float f32x4 __attribute__((ext_vector_type(4)));

// ---- fast hardware math (validated against bf16-level 2e-2 tolerance) ----
__device__ __forceinline__ float frcp(float x)  { return __builtin_amdgcn_rcpf(x); }
__device__ __forceinline__ float fsqrt(float x) { return __builtin_amdgcn_sqrtf(x); }
// v_sin_f32 takes revolutions: sin(x) = v_sin(x / 2pi). Args here are in
// [0, pi/2] -> |rev| <= 0.25, no range reduction needed.
__device__ __forceinline__ float fsin(float x)  { return __builtin_amdgcn_sinf(x * 0.15915494309189535f); }
// acos(x), x in [0,1]: Abramowitz-Stegun 4.4.45, max err 6.7e-5 rad.
__device__ __forceinline__ float facos(float x) {
    float p = fmaf(x, -0.0187293f, 0.0742610f);
    p = fmaf(x, p, -0.2121144f);
    p = fmaf(x, p, 1.5707288f);
    return fsqrt(1.0f - x) * p;
}
__device__ __forceinline__ float fsigmoid(float z) {
    // 1/(1+e^-z) = 1/(1+2^(-z*log2 e))
    return frcp(1.0f + __builtin_amdgcn_exp2f(-z * 1.44269504088896f));
}

// Per-voxel math, port of the JAX reference (f32) with fast approximations.
__device__ __forceinline__ void voxel_math(
    float qw, float qx, float qy, float qz,        // q channels
    float pw, float px, float py, float pz,        // q_ref channels
    float r0, float r1, float r2,                  // r channels (K=3)
    float rr0, float rr1, float rr2,               // r_ref channels
    float gw0, float gw1, float gw2, float gw3, float gb,
    float* U9, float* R3, float* Q4)
{
    // qv = q / (||q|| + EPS)
    float inv = frcp(fsqrt(qw*qw + qx*qx + qy*qy + qz*qz) + EPSF);
    float aw = qw*inv, ax = qx*inv, ay = qy*inv, az = qz*inv;
    inv = frcp(fsqrt(pw*pw + px*px + py*py + pz*pz) + EPSF);
    float bw = pw*inv, bx = px*inv, by = py*inv, bz = pz*inv;

    // c = clip(|<qv,qv_ref>|, 0, 1)
    float d0 = aw*bw + ax*bx + ay*by + az*bz;
    float c  = fminf(fabsf(d0), 1.0f);

    // gate: omega = sigmoid(gw0*r_mean + gw1*r_mean_ref + gw2*c + gw3 + gb)
    float rm   = (r0 + r1 + r2)   * (1.0f / 3.0f);
    float rmr  = (rr0 + rr1 + rr2) * (1.0f / 3.0f);
    float zlin = gw0*rm + gw1*rmr + gw2*c + gw3 + gb;
    float omega = fsigmoid(zlin);

    // slerp(qv, qv_ref, t=omega)
    float sgn = (d0 < 0.0f) ? -1.0f : 1.0f;
    float q1w = sgn*bw, q1x = sgn*bx, q1y = sgn*by, q1z = sgn*bz;
    float dd    = fminf(fabsf(d0), 1.0f - 1e-7f);
    float theta = facos(dd);
    float st    = fsin(theta);
    bool  small = st < 1e-4f;
    float invsafe = small ? 1.0f : frcp(st);
    float t  = omega;
    float s0 = fsin(t * theta);
    float s1 = fsin((1.0f - t) * theta);

    float sw = (s0*aw + s1*q1w) * invsafe;
    float sx = (s0*ax + s1*q1x) * invsafe;
    float sy = (s0*ay + s1*q1y) * invsafe;
    float sz = (s0*az + s1*q1z) * invsafe;
    float lw = t*aw + (1.0f - t)*q1w;
    float lx = t*ax + (1.0f - t)*q1x;
    float ly = t*ay + (1.0f - t)*q1y;
    float lz = t*az + (1.0f - t)*q1z;
    float ow = small ? lw : sw;
    float ox = small ? lx : sx;
    float oy = small ? ly : sy;
    float oz = small ? lz : sz;

    // q_bar = out / (||out|| + EPS)
    inv = frcp(fsqrt(ow*ow + ox*ox + oy*oy + oz*oz) + EPSF);
    float w = ow*inv, x = ox*inv, y = oy*inv, z = oz*inv;

    Q4[0] = w; Q4[1] = x; Q4[2] = y; Q4[3] = z;

    // R_bar from quaternion
    float xx = x*x, yy = y*y, zz = z*z;
    float xy = x*y, xz = x*z, yz = y*z;
    float wx = w*x, wy = w*y, wz = w*z;
    float m00 = 1.0f - 2.0f*(yy + zz), m01 = 2.0f*(xy - wz), m02 = 2.0f*(xz + wy);
    float m10 = 2.0f*(xy + wz), m11 = 1.0f - 2.0f*(xx + zz), m12 = 2.0f*(yz - wx);
    float m20 = 2.0f*(xz - wy), m21 = 2.0f*(yz + wx), m22 = 1.0f - 2.0f*(xx + yy);

    // Rn: normalize each COLUMN j (norm over row axis), +EPS
    float c0 = frcp(fsqrt(m00*m00 + m10*m10 + m20*m20) + EPSF);
    float c1 = frcp(fsqrt(m01*m01 + m11*m11 + m21*m21) + EPSF);
    float c2 = frcp(fsqrt(m02*m02 + m12*m12 + m22*m22) + EPSF);

    // U_bar[b, j, i, ...] = Rn[i][j]  (channel index = j*3 + i)
    U9[0] = m00*c0; U9[1] = m10*c0; U9[2] = m20*c0;   // j=0
    U9[3] = m01*c1; U9[4] = m11*c1; U9[5] = m21*c1;   // j=1
    U9[6] = m02*c2; U9[7] = m12*c2; U9[8] = m22*c2;   // j=2

    // r_bar = omega*r + (1-omega)*r_ref
    float om1 = 1.0f - omega;
    R3[0] = omega*r0 + om1*rr0;
    R3[1] = omega*r1 + om1*rr1;
    R3[2] = omega*r2 + om1*rr2;
}

__global__ __launch_bounds__(256) void ConsensusField3D_78013785964619_kernel(
    const float* __restrict__ r,
    const float* __restrict__ q,
    const float* __restrict__ r_ref,
    const float* __restrict__ q_ref,
    const float* __restrict__ gate_w,
    const float* __restrict__ gate_b,
    float* __restrict__ out)
{
    int idx = blockIdx.x * blockDim.x + threadIdx.x;
    if (idx >= kB * kS4) return;
    int b  = idx / kS4;
    int s4 = idx - b * kS4;

    const f32x4* q4  = (const f32x4*)q;
    const f32x4* p4  = (const f32x4*)q_ref;
    const f32x4* ra4 = (const f32x4*)r;
    const f32x4* rb4 = (const f32x4*)r_ref;

    // Coalesced float4 loads: 4 consecutive voxels per thread, per channel.
    f32x4 vqw = q4[(b*4 + 0)*kS4 + s4];
    f32x4 vqx = q4[(b*4 + 1)*kS4 + s4];
    f32x4 vqy = q4[(b*4 + 2)*kS4 + s4];
    f32x4 vqz = q4[(b*4 + 3)*kS4 + s4];
    f32x4 vpw = p4[(b*4 + 0)*kS4 + s4];
    f32x4 vpx = p4[(b*4 + 1)*kS4 + s4];
    f32x4 vpy = p4[(b*4 + 2)*kS4 + s4];
    f32x4 vpz = p4[(b*4 + 3)*kS4 + s4];
    f32x4 vr0 = ra4[(b*3 + 0)*kS4 + s4];
    f32x4 vr1 = ra4[(b*3 + 1)*kS4 + s4];
    f32x4 vr2 = ra4[(b*3 + 2)*kS4 + s4];
    f32x4 vs0 = rb4[(b*3 + 0)*kS4 + s4];
    f32x4 vs1 = rb4[(b*3 + 1)*kS4 + s4];
    f32x4 vs2 = rb4[(b*3 + 2)*kS4 + s4];

    float gw0 = gate_w[0], gw1 = gate_w[1], gw2 = gate_w[2], gw3 = gate_w[3];
    float gb  = gate_b[0];

    float U9[9][4], R3[3][4], Q4[4][4];

    #pragma unroll
    for (int j = 0; j < 4; ++j) {
        float u[9], rb_[3], qb_[4];
        voxel_math(vqw[j], vqx[j], vqy[j], vqz[j],
                   vpw[j], vpx[j], vpy[j], vpz[j],
                   vr0[j], vr1[j], vr2[j],
                   vs0[j], vs1[j], vs2[j],
                   gw0, gw1, gw2, gw3, gb,
                   u, rb_, qb_);
        #pragma unroll
        for (int k = 0; k < 9; ++k) U9[k][j] = u[k];
        #pragma unroll
        for (int k = 0; k < 3; ++k) R3[k][j] = rb_[k];
        #pragma unroll
        for (int k = 0; k < 4; ++k) Q4[k][j] = qb_[k];
    }

    f32x4* o4 = (f32x4*)out;
    const int RB = kB * 9 * kS4;        // start of r_bar, in float4 units
    const int QB = RB + kB * 3 * kS4;   // start of q_out

    // Outputs are streaming (never re-read): nontemporal stores keep the
    // input planes resident in L3 across graph replays.
    #pragma unroll
    for (int ch = 0; ch < 9; ++ch) {
        f32x4 v = {U9[ch][0], U9[ch][1], U9[ch][2], U9[ch][3]};
        __builtin_nontemporal_store(v, &o4[(b*9 + ch)*kS4 + s4]);
    }
    #pragma unroll
    for (int ch = 0; ch < 3; ++ch) {
        f32x4 v = {R3[ch][0], R3[ch][1], R3[ch][2], R3[ch][3]};
        __builtin_nontemporal_store(v, &o4[RB + (b*3 + ch)*kS4 + s4]);
    }
    #pragma unroll
    for (int ch = 0; ch < 4; ++ch) {
        f32x4 v = {Q4[ch][0], Q4[ch][1], Q4[ch][2], Q4[ch][3]};
        __builtin_nontemporal_store(v, &o4[QB + (b*4 + ch)*kS4 + s4]);
    }
}

extern "C" void kernel_launch(void* const* d_in, const int* in_sizes, int n_in,
                              void* d_out, int out_size, void* d_ws, size_t ws_size,
                              hipStream_t stream) {
    // Input order per setup_inputs: U(0), r(1), q(2), U_ref(3), r_ref(4), q_ref(5),
    // gate_w(6), gate_b(7). U and U_ref are DEAD (never used by the reference).
    const float* r      = (const float*)d_in[1];
    const float* q      = (const float*)d_in[2];
    const float* r_ref  = (const float*)d_in[4];
    const float* q_ref  = (const float*)d_in[5];
    const float* gate_w = (const float*)d_in[6];
    const float* gate_b = (const float*)d_in[7];
    float* out = (float*)d_out;

    const int total  = kB * kS4;              // 442368 threads
    const int block  = 256;
    const int grid   = (total + block - 1) / block;
    ConsensusField3D_78013785964619_kernel<<<grid, block, 0, stream>>>(
        r, q, r_ref, q_ref, gate_w, gate_b, out);
}

// Round 4
// 36.768 us; speedup vs baseline: 1.1553x; 1.0011x over previous
//
#include <hip/hip_runtime.h>
#include <math.h>

#define EPSF 1e-6f

// Problem constants (fixed by setup_inputs): B=2, K=3, D=H=W=96.
constexpr int kB   = 2;
constexpr int kS   = 96 * 96 * 96;   // spatial voxels per batch = 884736
constexpr int kS4  = kS / 4;         // float4 units per channel plane = 221184
constexpr int kBPB = kS4 / 512;      // blocks per batch (512 quads/block) = 432

// Native vector type for nontemporal stores (__builtin_nontemporal_store
// rejects HIP's class-type float4).
typedef float f32x4 __attribute__((ext_vector_type(4)));

// ---- fast hardware math (validated against bf16-level 2e-2 tolerance) ----
__device__ __forceinline__ float frcp(float x)  { return __builtin_amdgcn_rcpf(x); }
__device__ __forceinline__ float fsqrt(float x) { return __builtin_amdgcn_sqrtf(x); }
// v_sin_f32 takes revolutions: sin(x) = v_sin(x / 2pi). Args here are in
// [0, pi/2] -> |rev| <= 0.25, no range reduction needed.
__device__ __forceinline__ float fsin(float x)  { return __builtin_amdgcn_sinf(x * 0.15915494309189535f); }
// acos(x), x in [0,1]: Abramowitz-Stegun 4.4.45, max err 6.7e-5 rad.
__device__ __forceinline__ float facos(float x) {
    float p = fmaf(x, -0.0187293f, 0.0742610f);
    p = fmaf(x, p, -0.2121144f);
    p = fmaf(x, p, 1.5707288f);
    return fsqrt(1.0f - x) * p;
}
__device__ __forceinline__ float fsigmoid(float z) {
    return frcp(1.0f + __builtin_amdgcn_exp2f(-z * 1.44269504088896f));
}

// Per-voxel math, port of the JAX reference (f32) with fast approximations.
__device__ __forceinline__ void voxel_math(
    float qw, float qx, float qy, float qz,        // q channels
    float pw, float px, float py, float pz,        // q_ref channels
    float r0, float r1, float r2,                  // r channels (K=3)
    float rr0, float rr1, float rr2,               // r_ref channels
    float gw0, float gw1, float gw2, float gw3, float gb,
    float* U9, float* R3, float* Q4)
{
    float inv = frcp(fsqrt(qw*qw + qx*qx + qy*qy + qz*qz) + EPSF);
    float aw = qw*inv, ax = qx*inv, ay = qy*inv, az = qz*inv;
    inv = frcp(fsqrt(pw*pw + px*px + py*py + pz*pz) + EPSF);
    float bw = pw*inv, bx = px*inv, by = py*inv, bz = pz*inv;

    float d0 = aw*bw + ax*bx + ay*by + az*bz;
    float c  = fminf(fabsf(d0), 1.0f);

    float rm   = (r0 + r1 + r2)   * (1.0f / 3.0f);
    float rmr  = (rr0 + rr1 + rr2) * (1.0f / 3.0f);
    float zlin = gw0*rm + gw1*rmr + gw2*c + gw3 + gb;
    float omega = fsigmoid(zlin);

    float sgn = (d0 < 0.0f) ? -1.0f : 1.0f;
    float q1w = sgn*bw, q1x = sgn*bx, q1y = sgn*by, q1z = sgn*bz;
    float dd    = fminf(fabsf(d0), 1.0f - 1e-7f);
    float theta = facos(dd);
    float st    = fsin(theta);
    bool  small = st < 1e-4f;
    float invsafe = small ? 1.0f : frcp(st);
    float t  = omega;
    float s0 = fsin(t * theta);
    float s1 = fsin((1.0f - t) * theta);

    float sw = (s0*aw + s1*q1w) * invsafe;
    float sx = (s0*ax + s1*q1x) * invsafe;
    float sy = (s0*ay + s1*q1y) * invsafe;
    float sz = (s0*az + s1*q1z) * invsafe;
    float lw = t*aw + (1.0f - t)*q1w;
    float lx = t*ax + (1.0f - t)*q1x;
    float ly = t*ay + (1.0f - t)*q1y;
    float lz = t*az + (1.0f - t)*q1z;
    float ow = small ? lw : sw;
    float ox = small ? lx : sx;
    float oy = small ? ly : sy;
    float oz = small ? lz : sz;

    inv = frcp(fsqrt(ow*ow + ox*ox + oy*oy + oz*oz) + EPSF);
    float w = ow*inv, x = ox*inv, y = oy*inv, z = oz*inv;

    Q4[0] = w; Q4[1] = x; Q4[2] = y; Q4[3] = z;

    float xx = x*x, yy = y*y, zz = z*z;
    float xy = x*y, xz = x*z, yz = y*z;
    float wx = w*x, wy = w*y, wz = w*z;
    float m00 = 1.0f - 2.0f*(yy + zz), m01 = 2.0f*(xy - wz), m02 = 2.0f*(xz + wy);
    float m10 = 2.0f*(xy + wz), m11 = 1.0f - 2.0f*(xx + zz), m12 = 2.0f*(yz - wx);
    float m20 = 2.0f*(xz - wy), m21 = 2.0f*(yz + wx), m22 = 1.0f - 2.0f*(xx + yy);

    float c0 = frcp(fsqrt(m00*m00 + m10*m10 + m20*m20) + EPSF);
    float c1 = frcp(fsqrt(m01*m01 + m11*m11 + m21*m21) + EPSF);
    float c2 = frcp(fsqrt(m02*m02 + m12*m12 + m22*m22) + EPSF);

    U9[0] = m00*c0; U9[1] = m10*c0; U9[2] = m20*c0;   // j=0
    U9[3] = m01*c1; U9[4] = m11*c1; U9[5] = m21*c1;   // j=1
    U9[6] = m02*c2; U9[7] = m12*c2; U9[8] = m22*c2;   // j=2

    float om1 = 1.0f - omega;
    R3[0] = omega*r0 + om1*rr0;
    R3[1] = omega*r1 + om1*rr1;
    R3[2] = omega*r2 + om1*rr2;
}

// Process one quad (4 voxels) given its 14 channel vectors; write outputs.
__device__ __forceinline__ void process_quad(
    f32x4 vqw, f32x4 vqx, f32x4 vqy, f32x4 vqz,
    f32x4 vpw, f32x4 vpx, f32x4 vpy, f32x4 vpz,
    f32x4 vr0, f32x4 vr1, f32x4 vr2,
    f32x4 vs0, f32x4 vs1, f32x4 vs2,
    float gw0, float gw1, float gw2, float gw3, float gb,
    f32x4* o4, int b, int s4)
{
    float U9[9][4], R3[3][4], Q4[4][4];
    #pragma unroll
    for (int j = 0; j < 4; ++j) {
        float u[9], rb_[3], qb_[4];
        voxel_math(vqw[j], vqx[j], vqy[j], vqz[j],
                   vpw[j], vpx[j], vpy[j], vpz[j],
                   vr0[j], vr1[j], vr2[j],
                   vs0[j], vs1[j], vs2[j],
                   gw0, gw1, gw2, gw3, gb, u, rb_, qb_);
        #pragma unroll
        for (int k = 0; k < 9; ++k) U9[k][j] = u[k];
        #pragma unroll
        for (int k = 0; k < 3; ++k) R3[k][j] = rb_[k];
        #pragma unroll
        for (int k = 0; k < 4; ++k) Q4[k][j] = qb_[k];
    }

    const int RB = kB * 9 * kS4;        // start of r_bar, in float4 units
    const int QB = RB + kB * 3 * kS4;   // start of q_out

    #pragma unroll
    for (int ch = 0; ch < 9; ++ch) {
        f32x4 v = {U9[ch][0], U9[ch][1], U9[ch][2], U9[ch][3]};
        __builtin_nontemporal_store(v, &o4[(b*9 + ch)*kS4 + s4]);
    }
    #pragma unroll
    for (int ch = 0; ch < 3; ++ch) {
        f32x4 v = {R3[ch][0], R3[ch][1], R3[ch][2], R3[ch][3]};
        __builtin_nontemporal_store(v, &o4[RB + (b*3 + ch)*kS4 + s4]);
    }
    #pragma unroll
    for (int ch = 0; ch < 4; ++ch) {
        f32x4 v = {Q4[ch][0], Q4[ch][1], Q4[ch][2], Q4[ch][3]};
        __builtin_nontemporal_store(v, &o4[QB + (b*4 + ch)*kS4 + s4]);
    }
}

__global__ __launch_bounds__(256) void ConsensusField3D_78013785964619_kernel(
    const float* __restrict__ r,
    const float* __restrict__ q,
    const float* __restrict__ r_ref,
    const float* __restrict__ q_ref,
    const float* __restrict__ gate_w,
    const float* __restrict__ gate_b,
    float* __restrict__ out)
{
    // Each block covers 512 consecutive quads: thread handles quads
    // base+tid and base+tid+256 (both loads fully wave-coalesced).
    int b    = blockIdx.x / kBPB;
    int bb   = blockIdx.x - b * kBPB;
    int sA   = bb * 512 + threadIdx.x;
    int sB   = sA + 256;

    const f32x4* q4  = (const f32x4*)q;
    const f32x4* p4  = (const f32x4*)q_ref;
    const f32x4* ra4 = (const f32x4*)r;
    const f32x4* rb4 = (const f32x4*)r_ref;

    // Issue ALL 28 independent loads upfront: 448 B in flight per lane
    // before the serial transcendental chain starts.
    f32x4 aqw = q4[(b*4 + 0)*kS4 + sA];
    f32x4 aqx = q4[(b*4 + 1)*kS4 + sA];
    f32x4 aqy = q4[(b*4 + 2)*kS4 + sA];
    f32x4 aqz = q4[(b*4 + 3)*kS4 + sA];
    f32x4 apw = p4[(b*4 + 0)*kS4 + sA];
    f32x4 apx = p4[(b*4 + 1)*kS4 + sA];
    f32x4 apy = p4[(b*4 + 2)*kS4 + sA];
    f32x4 apz = p4[(b*4 + 3)*kS4 + sA];
    f32x4 ar0 = ra4[(b*3 + 0)*kS4 + sA];
    f32x4 ar1 = ra4[(b*3 + 1)*kS4 + sA];
    f32x4 ar2 = ra4[(b*3 + 2)*kS4 + sA];
    f32x4 as0 = rb4[(b*3 + 0)*kS4 + sA];
    f32x4 as1 = rb4[(b*3 + 1)*kS4 + sA];
    f32x4 as2 = rb4[(b*3 + 2)*kS4 + sA];

    f32x4 bqw = q4[(b*4 + 0)*kS4 + sB];
    f32x4 bqx = q4[(b*4 + 1)*kS4 + sB];
    f32x4 bqy = q4[(b*4 + 2)*kS4 + sB];
    f32x4 bqz = q4[(b*4 + 3)*kS4 + sB];
    f32x4 bpw = p4[(b*4 + 0)*kS4 + sB];
    f32x4 bpx = p4[(b*4 + 1)*kS4 + sB];
    f32x4 bpy = p4[(b*4 + 2)*kS4 + sB];
    f32x4 bpz = p4[(b*4 + 3)*kS4 + sB];
    f32x4 br0 = ra4[(b*3 + 0)*kS4 + sB];
    f32x4 br1 = ra4[(b*3 + 1)*kS4 + sB];
    f32x4 br2 = ra4[(b*3 + 2)*kS4 + sB];
    f32x4 bs0 = rb4[(b*3 + 0)*kS4 + sB];
    f32x4 bs1 = rb4[(b*3 + 1)*kS4 + sB];
    f32x4 bs2 = rb4[(b*3 + 2)*kS4 + sB];

    float gw0 = gate_w[0], gw1 = gate_w[1], gw2 = gate_w[2], gw3 = gate_w[3];
    float gb  = gate_b[0];

    f32x4* o4 = (f32x4*)out;

    process_quad(aqw, aqx, aqy, aqz, apw, apx, apy, apz,
                 ar0, ar1, ar2, as0, as1, as2,
                 gw0, gw1, gw2, gw3, gb, o4, b, sA);
    process_quad(bqw, bqx, bqy, bqz, bpw, bpx, bpy, bpz,
                 br0, br1, br2, bs0, bs1, bs2,
                 gw0, gw1, gw2, gw3, gb, o4, b, sB);
}

extern "C" void kernel_launch(void* const* d_in, const int* in_sizes, int n_in,
                              void* d_out, int out_size, void* d_ws, size_t ws_size,
                              hipStream_t stream) {
    // Input order per setup_inputs: U(0), r(1), q(2), U_ref(3), r_ref(4), q_ref(5),
    // gate_w(6), gate_b(7). U and U_ref are DEAD (never used by the reference).
    const float* r      = (const float*)d_in[1];
    const float* q      = (const float*)d_in[2];
    const float* r_ref  = (const float*)d_in[4];
    const float* q_ref  = (const float*)d_in[5];
    const float* gate_w = (const float*)d_in[6];
    const float* gate_b = (const float*)d_in[7];
    float* out = (float*)d_out;

    const int grid = kB * kBPB;   // 864 blocks, 512 quads each
    ConsensusField3D_78013785964619_kernel<<<grid, 256, 0, stream>>>(
        r, q, r_ref, q_ref, gate_w, gate_b, out);
}